// Round 1
// baseline (21035.141 us; speedup 1.0000x reference)
//
#include <hip/hip_runtime.h>

#define TSTEPS 512
#define BATCH  256
#define HID    256
#define OUTC   256

typedef _Float16 half8 __attribute__((ext_vector_type(8)));
typedef float    f32x4 __attribute__((ext_vector_type(4)));

__device__ __forceinline__ float sigf(float x){ return 1.0f/(1.0f+__expf(-x)); }
__device__ __forceinline__ float tanh_(float x){
  float a = fminf(fmaxf(x,-8.0f),8.0f);
  float e = __expf(2.0f*a);
  return (e-1.0f)/(e+1.0f);
}
// 16B-granule XOR swizzle: spreads same-granule column reads across banks
__device__ __forceinline__ int swz(int row, int g){ return g ^ (row & 7); }

// ---------------- prep: f32 -> f16 weight conversion + bias fold ----------------
__global__ void prep_convert(const float* __restrict__ Wih, const float* __restrict__ Whh,
                             const float* __restrict__ fcw, const float* __restrict__ bih,
                             const float* __restrict__ bhh,
                             _Float16* __restrict__ wh0, _Float16* __restrict__ wi1,
                             _Float16* __restrict__ wh1, _Float16* __restrict__ fcwh,
                             float* __restrict__ bias1)
{
  int i = blockIdx.x*256 + threadIdx.x;          // grid covers exactly 262144
  wh0[i] = (_Float16)Whh[i];                     // W_hh[0]
  wi1[i] = (_Float16)Wih[262144 + i];            // W_ih[1]
  wh1[i] = (_Float16)Whh[262144 + i];            // W_hh[1]
  if (i < 65536) fcwh[i] = (_Float16)fcw[i];
  if (i < 1024)  bias1[i] = bih[1024+i] + bhh[1024+i];
}

// ---------------- prep: gx0[b][n] = x[b]·W_ih0[n] + b_ih0[n] + b_hh0[n] (f32) ----
__global__ void prep_gx0(const float* __restrict__ x, const float* __restrict__ Wih,
                         const float* __restrict__ bih, const float* __restrict__ bhh,
                         float* __restrict__ gx0)
{
  int gid = blockIdx.x*256 + threadIdx.x;        // 262144 outputs
  int b = gid >> 10, n = gid & 1023;
  const float4* xv = (const float4*)(x + (size_t)b*256);
  const float4* wv = (const float4*)(Wih + (size_t)n*256);
  float s = bih[n] + bhh[n];
  #pragma unroll 8
  for (int k=0;k<64;k++){
    float4 a = xv[k], c = wv[k];
    s += a.x*c.x + a.y*c.y + a.z*c.z + a.w*c.w;
  }
  gx0[gid] = s;
}

// ---------------- persistent LSTM: 16 WGs, one 16-row batch tile each ----------------
// wave w (of 8) owns hidden cols [w*32, w*32+32); lane: col=l&15, kg=l>>4
// MFMA C layout (gfx950, verified): C[row=(l>>4)*4+reg][col=l&15]
__global__ __launch_bounds__(512) void lstm_kernel(
    const float* __restrict__ gx0, const _Float16* __restrict__ Wh0,
    const _Float16* __restrict__ Wi1, const _Float16* __restrict__ Wh1,
    const float* __restrict__ bias1, const float* __restrict__ h0_in,
    const float* __restrict__ c0_in, _Float16* __restrict__ seq, int pitch)
{
  __shared__ __align__(16) _Float16 sh0[16][256];   // h of layer 0 (swizzled)
  __shared__ __align__(16) _Float16 sh1[16][256];   // h of layer 1 (swizzled)
  const int b0  = blockIdx.x * 16;
  const int tid = threadIdx.x;
  const int w   = tid >> 6;
  const int l   = tid & 63;
  const int col = l & 15;
  const int kg  = l >> 4;

  // init h state into LDS (one 8-elem chunk per thread)
  {
    int r = tid >> 5, g = tid & 31;
    const float* s0 = h0_in + (size_t)(b0 + r)*256 + g*8;
    const float* s1 = s0 + 65536;                 // layer 1
    half8 v0, v1;
    #pragma unroll
    for (int q=0;q<8;q++){ v0[q] = (_Float16)s0[q]; v1[q] = (_Float16)s1[q]; }
    *(half8*)&sh0[r][swz(r,g)*8] = v0;
    *(half8*)&sh1[r][swz(r,g)*8] = v1;
  }

  // per-lane state: (b = kg*4+r, j = w*32 + jt*16 + col), jt in {0,1}
  float c0r[2][4], c1r[2][4];
  float gx[2][4][4];   // loop-invariant layer-0 gate bias+input term [jt][g][r]
  float b1r[2][4];     // layer-1 bias [jt][g]
  #pragma unroll
  for (int jt=0;jt<2;jt++){
    int jc = w*32 + jt*16 + col;
    #pragma unroll
    for (int r=0;r<4;r++){
      int b = b0 + kg*4 + r;
      c0r[jt][r] = c0_in[(size_t)b*256 + jc];
      c1r[jt][r] = c0_in[65536 + (size_t)b*256 + jc];
      #pragma unroll
      for (int g=0;g<4;g++) gx[jt][g][r] = gx0[(size_t)b*1024 + g*256 + jc];
    }
    #pragma unroll
    for (int g=0;g<4;g++) b1r[jt][g] = bias1[g*256 + jc];
  }
  __syncthreads();

  for (int t=0; t<TSTEPS; ++t){
    // ---- layer 0: gates = gx0 + h0 @ Wh0.T ----
    half8 a0[8];
    #pragma unroll
    for (int kt=0;kt<8;kt++) a0[kt] = *(const half8*)&sh0[col][swz(col, kt*4+kg)*8];
    __syncthreads();
    #pragma unroll
    for (int jt=0;jt<2;jt++){
      int jc = w*32 + jt*16 + col;
      f32x4 acc[4];
      #pragma unroll
      for (int g=0;g<4;g++){
        f32x4 a;
        #pragma unroll
        for (int r=0;r<4;r++) a[r] = gx[jt][g][r];
        const _Float16* wr = Wh0 + (size_t)(g*256 + jc)*256;
        #pragma unroll
        for (int kt=0;kt<8;kt++){
          half8 bf = *(const half8*)&wr[kt*32 + kg*8];
          a = __builtin_amdgcn_mfma_f32_16x16x32_f16(a0[kt], bf, a, 0,0,0);
        }
        acc[g] = a;
      }
      #pragma unroll
      for (int r=0;r<4;r++){
        float iv = sigf(acc[0][r]);
        float fv = sigf(acc[1][r]);
        float gv = tanh_(acc[2][r]);
        float ov = sigf(acc[3][r]);
        float cn = fv*c0r[jt][r] + iv*gv;
        c0r[jt][r] = cn;
        float hn = ov*tanh_(cn);
        int b = kg*4 + r;
        sh0[b][swz(b, jc>>3)*8 + (jc&7)] = (_Float16)hn;
      }
    }
    __syncthreads();
    // ---- layer 1: gates = [h0_new, h1_prev] @ [Wi1; Wh1].T + bias1 ----
    half8 a1[16];
    #pragma unroll
    for (int kt=0;kt<8;kt++) a1[kt]   = *(const half8*)&sh0[col][swz(col, kt*4+kg)*8];
    #pragma unroll
    for (int kt=0;kt<8;kt++) a1[8+kt] = *(const half8*)&sh1[col][swz(col, kt*4+kg)*8];
    __syncthreads();
    #pragma unroll
    for (int jt=0;jt<2;jt++){
      int jc = w*32 + jt*16 + col;
      f32x4 acc[4];
      #pragma unroll
      for (int g=0;g<4;g++){
        float bv = b1r[jt][g];
        f32x4 a = {bv,bv,bv,bv};
        const _Float16* wi = Wi1 + (size_t)(g*256 + jc)*256;
        const _Float16* wh = Wh1 + (size_t)(g*256 + jc)*256;
        #pragma unroll
        for (int kt=0;kt<8;kt++){
          half8 bf = *(const half8*)&wi[kt*32 + kg*8];
          a = __builtin_amdgcn_mfma_f32_16x16x32_f16(a1[kt], bf, a, 0,0,0);
        }
        #pragma unroll
        for (int kt=0;kt<8;kt++){
          half8 bf = *(const half8*)&wh[kt*32 + kg*8];
          a = __builtin_amdgcn_mfma_f32_16x16x32_f16(a1[8+kt], bf, a, 0,0,0);
        }
        acc[g] = a;
      }
      #pragma unroll
      for (int r=0;r<4;r++){
        float iv = sigf(acc[0][r]);
        float fv = sigf(acc[1][r]);
        float gv = tanh_(acc[2][r]);
        float ov = sigf(acc[3][r]);
        float cn = fv*c1r[jt][r] + iv*gv;
        c1r[jt][r] = cn;
        float hn = ov*tanh_(cn);
        int b = kg*4 + r;
        sh1[b][swz(b, jc>>3)*8 + (jc&7)] = (_Float16)hn;
      }
    }
    __syncthreads();
    // ---- publish h1(t) to seq ----
    {
      int r = tid >> 5, g = tid & 31;
      half8 v = *(const half8*)&sh1[r][swz(r,g)*8];
      *(half8*)&seq[((size_t)(b0 + r)*TSTEPS + t)*pitch + g*8] = v;
    }
  }
}

// ---------------- FC + log_softmax / softmax ----------------
__global__ __launch_bounds__(256) void fc_kernel(
    const _Float16* __restrict__ seq, int pitch,
    const _Float16* __restrict__ fcwh, const float* __restrict__ fcb,
    float* __restrict__ out0, float* __restrict__ out1)
{
  const int tid = threadIdx.x;
  const int w = tid >> 6, l = tid & 63;
  const int col = l & 15, kg = l >> 4;
  const size_t m0 = (size_t)blockIdx.x*64 + (size_t)w*16;   // flat (b*T+t) row base
  half8 a[8];
  #pragma unroll
  for (int kt=0;kt<8;kt++)
    a[kt] = *(const half8*)&seq[(m0+col)*(size_t)pitch + kt*32 + kg*8];
  f32x4 acc[16];
  #pragma unroll
  for (int nt=0;nt<16;nt++){
    int n = nt*16 + col;
    float bv = fcb[n];
    f32x4 c = {bv,bv,bv,bv};
    const _Float16* wr = fcwh + (size_t)n*256;
    #pragma unroll
    for (int kt=0;kt<8;kt++){
      half8 bf = *(const half8*)&wr[kt*32 + kg*8];
      c = __builtin_amdgcn_mfma_f32_16x16x32_f16(a[kt], bf, c, 0,0,0);
    }
    acc[nt] = c;
  }
  // per-row softmax: row = m0 + kg*4 + r, held by the 16 lanes sharing kg
  #pragma unroll
  for (int r=0;r<4;r++){
    float mx = -3.0e38f;
    #pragma unroll
    for (int nt=0;nt<16;nt++) mx = fmaxf(mx, acc[nt][r]);
    #pragma unroll
    for (int off=1; off<16; off<<=1) mx = fmaxf(mx, __shfl_xor(mx, off, 64));
    float s = 0.0f;
    #pragma unroll
    for (int nt=0;nt<16;nt++) s += __expf(acc[nt][r]-mx);
    #pragma unroll
    for (int off=1; off<16; off<<=1) s += __shfl_xor(s, off, 64);
    float inv = 1.0f/s;
    float ls  = __logf(s);
    size_t row = m0 + (size_t)kg*4 + r;
    #pragma unroll
    for (int nt=0;nt<16;nt++){
      int n = nt*16 + col;
      float v = acc[nt][r]-mx;
      out0[row*256 + n] = v - ls;        // log_softmax
      out1[row*256 + n] = __expf(v)*inv; // softmax
    }
  }
}

extern "C" void kernel_launch(void* const* d_in, const int* in_sizes, int n_in,
                              void* d_out, int out_size, void* d_ws, size_t ws_size,
                              hipStream_t stream)
{
  const float* x   = (const float*)d_in[0];
  const float* h0  = (const float*)d_in[1];
  const float* c0  = (const float*)d_in[2];
  const float* Wih = (const float*)d_in[3];
  const float* Whh = (const float*)d_in[4];
  const float* bih = (const float*)d_in[5];
  const float* bhh = (const float*)d_in[6];
  const float* fcw = (const float*)d_in[7];
  const float* fcb = (const float*)d_in[8];
  (void)in_sizes; (void)n_in; (void)out_size;   // T=512 fixed by problem

  char* ws = (char*)d_ws;
  _Float16* wh0   = (_Float16*)(ws + 0);            // 512 KB
  _Float16* wi1   = (_Float16*)(ws + (512<<10));    // 512 KB
  _Float16* wh1   = (_Float16*)(ws + (1024<<10));   // 512 KB
  _Float16* fcwh  = (_Float16*)(ws + (1536<<10));   // 128 KB
  float*    bias1 = (float*)   (ws + (1664<<10));   // 4 KB
  float*    gx0   = (float*)   (ws + (1668<<10));   // 1 MB

  const size_t SEQ_OFF   = 3ull<<20;
  const size_t seq_bytes = (size_t)BATCH*TSTEPS*HID*sizeof(_Float16); // 64 MB
  float* out0 = (float*)d_out;
  float* out1 = out0 + (size_t)BATCH*TSTEPS*OUTC;
  _Float16* seq; int pitch;
  if (ws_size >= SEQ_OFF + seq_bytes){
    seq = (_Float16*)(ws + SEQ_OFF); pitch = HID;   // packed in workspace
  } else {
    // overlay seq (f16, 512B/row) inside out1's 1KB/row slots; fc_kernel
    // reads each row into registers before overwriting the slot (same wave).
    seq = (_Float16*)out1; pitch = 512;
  }

  hipLaunchKernelGGL(prep_convert, dim3(1024), dim3(256), 0, stream,
                     Wih, Whh, fcw, bih, bhh, wh0, wi1, wh1, fcwh, bias1);
  hipLaunchKernelGGL(prep_gx0, dim3(1024), dim3(256), 0, stream,
                     x, Wih, bih, bhh, gx0);
  hipLaunchKernelGGL(lstm_kernel, dim3(16), dim3(512), 0, stream,
                     gx0, wh0, wi1, wh1, bias1, h0, c0, seq, pitch);
  hipLaunchKernelGGL(fc_kernel, dim3(2048), dim3(256), 0, stream,
                     seq, pitch, fcwh, fcb, out0, out1);
}